// Round 10
// baseline (171.036 us; speedup 1.0000x reference)
//
#include <hip/hip_runtime.h>

// Involution (B=8, H=W=192, C=64, G=4, K=3, R=4) — round 13.
// R12 post-mortem: WIN (73->69.5 profiled, harness 168.9 best; VGPR 76,
// no spill, 0 conflicts). Confirmed harness = profiled + ~100us fixed.
// Still latency-bound (VALU 24%, HBM 25%, occ 24%): block lifetime ~29us
// for ~3us of issue work. Remaining structural serializer: the single
// __syncthreads — full vmcnt(0)+lgkmcnt(0) drain + wave0/wave1 lockstep,
// needed only because Phase A's pixel map (tid&15 cols) makes each wave
// consume the OTHER wave's s_kern entries.
// R13: wave-decoupled, ZERO barriers. Phase A remap: wave w's lane ln
// generates pixel (row ln>>3, col tw0+8w+(ln&7)) — exactly the 64 px
// whose kern wave w consumes in Phase B. s_kern = two wave-private
// halves; same-wave ds_write->ds_read is program-ordered (lgkmcnt), so
// the barrier is DELETED. Waves run start-to-finish independent: no
// drain, no lockstep, natural stagger on the CU.
// Phase B per wave = R12 verbatim: adjacent col pairs (2j,2j+1), 4-tap
// ring rg[4][4], mask-0 fences, prologue loads before first COMP,
// identical store/kq patterns (j=ln>>4 reproduces R12's wslot layout).
// GATES: VGPR 70-90, WRITE == 73728, conflicts ~0, LDS 18432.
// Predict profiled 69.5 -> 58-65us, harness -> 158-166. If flat:
// cross-wave coupling wasn't the cost -> next lever is ring depth 5 /
// prefetch distance 3.

#define B_   8
#define H_   192
#define W_   192
#define CR_  16
#define TH_  8
#define TW_  16
#define TILES_X (W_/TW_)                    // 12
#define TILES_PER_IMG (TILES_X*(H_/TH_))    // 288
#define NBLK (B_*TILES_PER_IMG)             // 2304

constexpr float BN_EPS = 1e-3f;

__device__ __forceinline__ float4 mask4(float4 k, bool v) {
    k.x = v ? k.x : 0.f;
    k.y = v ? k.y : 0.f;
    k.z = v ? k.z : 0.f;
    k.w = v ? k.w : 0.f;
    return k;
}

__device__ __forceinline__ void fma4(float4& a, const float4 k, const float4 x) {
    a.x = fmaf(k.x, x.x, a.x);
    a.y = fmaf(k.y, x.y, a.y);
    a.z = fmaf(k.z, x.z, a.z);
    a.w = fmaf(k.w, x.w, a.w);
}

// Load row R (clamped) into ring slot S: 4 tap-columns {wA-1..wA+2}.
#define LROWS(S, R)                                                         \
    do {                                                                    \
        int rr_ = (R);                                                      \
        if (!INTERIOR) {                                                    \
            if ((unsigned)rr_ < (unsigned)H_) rv |= (1 << (S));             \
            else                              rv &= ~(1 << (S));            \
            rr_ = rr_ < 0 ? 0 : (rr_ >= H_ ? H_ - 1 : rr_);                 \
        }                                                                   \
        const int rb_ = rr_ * (W_ * 16);                                    \
        rg[S][0] = x4[rb_ + co[0]];                                         \
        rg[S][1] = x4[rb_ + co[1]];                                         \
        rg[S][2] = x4[rb_ + co[2]];                                         \
        rg[S][3] = x4[rb_ + co[3]];                                         \
    } while (0)

// Compute pixel row th0+I, output cols wA (taps 0..2) and wA+1 (taps 1..3).
// kq from THIS WAVE's private s_kern half: wave-local pixel p = I*8 + 2j.
#define COMP(I)                                                             \
    do {                                                                    \
        const float4* kqA_ = &s_half[((I) * 8 + 2 * j) * 9];                \
        const float4* kqB_ = kqA_ + 9;                                      \
        float4 aA_ = make_float4(0.f, 0.f, 0.f, 0.f);                       \
        float4 aB_ = make_float4(0.f, 0.f, 0.f, 0.f);                       \
        _Pragma("unroll")                                                   \
        for (int ti_ = 0; ti_ < 3; ++ti_) {                                 \
            const int s_ = ((I) + ti_) & 3;                                 \
            _Pragma("unroll")                                               \
            for (int tj_ = 0; tj_ < 3; ++tj_) {                             \
                float4 kA_ = kqA_[ti_ * 3 + tj_];                           \
                float4 kB_ = kqB_[ti_ * 3 + tj_];                           \
                if (!INTERIOR) {                                            \
                    kA_ = mask4(kA_, (((rv >> s_) & (cm >> tj_)) & 1));     \
                    kB_ = mask4(kB_, (((rv >> s_) & (cm >> (tj_ + 1))) & 1));\
                }                                                           \
                fma4(aA_, kA_, rg[s_][tj_]);                                \
                fma4(aB_, kB_, rg[s_][tj_ + 1]);                            \
            }                                                               \
        }                                                                   \
        const int ob_ = (th0 + (I)) * (W_ * 16);                            \
        o4[ob_ + (wA << 4) + c4i] = aA_;                                    \
        o4[ob_ + (wA << 4) + 16 + c4i] = aB_;                               \
    } while (0)

#define SFENCE __builtin_amdgcn_sched_barrier(0)

// Per-wave Phase B: cols tw0w .. tw0w+7 (this wave's 8 columns), rows
// th0..th0+7. No cross-wave data, no barriers.
template <bool INTERIOR>
__device__ __forceinline__ void phase_b(const float4* __restrict__ x4,
                                        float4* __restrict__ o4,
                                        const float4* __restrict__ s_half,
                                        int th0, int tw0w, int ln)
{
    const int j   = ln >> 4;      // col pair 0..3 -> cols 2j, 2j+1
    const int c4i = ln & 15;      // float4 channel chunk
    const int wA  = tw0w + 2 * j;

    // 4 tap-column float4-offsets {wA-1 .. wA+2} (clamped; validity
    // zeroes the kern weight, matching zero-padding semantics).
    int co[4];
    int cm = 0xF;
    #pragma unroll
    for (int tj = 0; tj < 4; ++tj) {
        int wc = wA - 1 + tj;
        if (!INTERIOR) {
            if ((unsigned)wc >= (unsigned)W_) cm &= ~(1 << tj);
            wc = wc < 0 ? 0 : (wc >= W_ ? W_ - 1 : wc);
        }
        co[tj] = (wc << 4) + c4i;
    }

    float4 rg[4][4];   // 64 VGPR ring, all indices static
    int rv = 0xF;

    // Prologue rows th0-1..th0+2. The first COMP's kq ds_reads wait on
    // this wave's own A2 ds_writes (fast, already in flight) and these
    // 16 global loads — one exposed latency per block, no barrier drain.
    LROWS(0, th0 - 1);
    LROWS(1, th0 + 0);
    LROWS(2, th0 + 1);
    LROWS(3, th0 + 2);

    SFENCE;
    // Steady state: region i = { COMP(i), prefetch row th0+i+3 } —
    // prefetch lands in the slot retired by COMP(i), first used by
    // COMP(i+2): two regions of FMA+LDS work after issue.
    COMP(0); LROWS(0, th0 + 3);
    SFENCE;
    COMP(1); LROWS(1, th0 + 4);
    SFENCE;
    COMP(2); LROWS(2, th0 + 5);
    SFENCE;
    COMP(3); LROWS(3, th0 + 6);
    SFENCE;
    COMP(4); LROWS(0, th0 + 7);
    SFENCE;
    COMP(5); LROWS(1, th0 + 8);
    SFENCE;
    COMP(6);
    COMP(7);
}

#undef LROWS
#undef COMP

__global__ __launch_bounds__(128, 2)
void invol_fused(const float* __restrict__ x,
                 const float* __restrict__ w1,
                 const float* __restrict__ b1,
                 const float* __restrict__ gamma,
                 const float* __restrict__ beta,
                 const float* __restrict__ mean,
                 const float* __restrict__ var,
                 const float* __restrict__ w2,
                 const float* __restrict__ b2,
                 float* __restrict__ out)
{
    // Two wave-private halves: 64 px * 9 float4 each = 18 KB total.
    // Wave w only ever touches s_kern[w] — no cross-wave hazard, ever.
    __shared__ float4 s_kern[2][64 * 9];

    const int bid = blockIdx.x;
    // XCD swizzle: 2304 = 8 * 288; each XCD owns one image for L2 locality.
    const int img = bid & 7;
    const int tin = bid >> 3;
    const int th0 = (tin / TILES_X) * TH_;
    const int tw0 = (tin % TILES_X) * TW_;
    const int tid = threadIdx.x;
    const int wv  = tid >> 6;            // wave 0/1
    const int ln  = tid & 63;            // lane

    const float4* x4 = reinterpret_cast<const float4*>(x) +
                       (size_t)img * (H_ * W_ * 16);
    float4* o4 = reinterpret_cast<float4*>(out) +
                 (size_t)img * (H_ * W_ * 16);

    // ---------------- Phase A: kernel generation (1 lane = 1 pixel) --------
    // Pixel map: lane ln of wave w -> (row ln>>3, col tw0+8w+(ln&7)) —
    // exactly the 64 px whose kern THIS wave consumes in Phase B.
    // Strided-direct global reads, deliberately (R10/R11: both LDS-staged
    // variants serialized the load->write->read chain and lost ~35us;
    // direct loads pipeline per-c4 with the w1 FMA chain).
    {
        const int r = ln >> 3, c8 = ln & 7;
        const int h = th0 + r, w = tw0 + 8 * wv + c8;
        const float4* xp = reinterpret_cast<const float4*>(
            x + (((size_t)((img * H_ + h) * W_ + w)) << 6));

        float td[CR_];
        #pragma unroll
        for (int d = 0; d < CR_; ++d) td[d] = 0.f;

        // t = x @ w1   (weight addresses wave-uniform -> s_load, SMEM pipe)
        #pragma unroll
        for (int c4 = 0; c4 < 16; ++c4) {
            const float4 xv = xp[c4];
            const float xs[4] = {xv.x, xv.y, xv.z, xv.w};
            #pragma unroll
            for (int k = 0; k < 4; ++k) {
                const float* wr = w1 + (c4 * 4 + k) * CR_;
                #pragma unroll
                for (int d = 0; d < CR_; ++d)
                    td[d] = fmaf(xs[k], wr[d], td[d]);
            }
        }

        // + b1, BN (inference), ReLU — folded affine
        #pragma unroll
        for (int d = 0; d < CR_; ++d) {
            const float a = gamma[d] * rsqrtf(var[d] + BN_EPS);
            const float c = (b1[d] - mean[d]) * a + beta[d];
            td[d] = fmaxf(fmaf(td[d], a, c), 0.f);
        }

        // kern = t @ w2 + b2  (e = tap*4 + g)
        float ke[36];
        #pragma unroll
        for (int e = 0; e < 36; ++e) ke[e] = b2[e];
        #pragma unroll
        for (int d = 0; d < CR_; ++d) {
            const float t = td[d];
            const float* wr = w2 + d * 36;
            #pragma unroll
            for (int e = 0; e < 36; ++e)
                ke[e] = fmaf(t, wr[e], ke[e]);
        }

        // Wave-private s_kern write: local pixel p = ln, stride 36 words
        // (144 B — measured 0 conflicts across all rounds).
        float4* skq = &s_kern[wv][ln * 9];
        #pragma unroll
        for (int t9 = 0; t9 < 9; ++t9)
            skq[t9] = make_float4(ke[t9 * 4 + 0], ke[t9 * 4 + 1],
                                  ke[t9 * 4 + 2], ke[t9 * 4 + 3]);
    }

    // NO __syncthreads: same-wave ds_write -> ds_read is ordered by
    // program order + lgkmcnt. Waves are fully decoupled from here on.

    // ---------------- Phase B: 9-tap multiply-reduce, adjacent col pairs ----
    const bool interior = (th0 > 0) && (th0 + TH_ < H_) &&
                          (tw0 > 0) && (tw0 + TW_ < W_);
    if (interior)
        phase_b<true >(x4, o4, s_kern[wv], th0, tw0 + 8 * wv, ln);
    else
        phase_b<false>(x4, o4, s_kern[wv], th0, tw0 + 8 * wv, ln);
}

extern "C" void kernel_launch(void* const* d_in, const int* in_sizes, int n_in,
                              void* d_out, int out_size, void* d_ws, size_t ws_size,
                              hipStream_t stream) {
    const float* x     = (const float*)d_in[0];
    const float* w1    = (const float*)d_in[1];
    const float* b1    = (const float*)d_in[2];
    const float* gamma = (const float*)d_in[3];
    const float* beta  = (const float*)d_in[4];
    const float* mean  = (const float*)d_in[5];
    const float* var   = (const float*)d_in[6];
    const float* w2    = (const float*)d_in[7];
    const float* b2    = (const float*)d_in[8];
    float* out = (float*)d_out;

    invol_fused<<<dim3(NBLK), dim3(128), 0, stream>>>(
        x, w1, b1, gamma, beta, mean, var, w2, b2, out);
}